// Round 2
// baseline (198.850 us; speedup 1.0000x reference)
//
#include <hip/hip_runtime.h>

typedef unsigned short u16;
typedef __attribute__((ext_vector_type(8))) short short8;
typedef __attribute__((ext_vector_type(4))) float f32x4;

#define B_  64
#define IC  64
#define OC  64
#define NG  2048
#define MD  512

__device__ inline u16 f2b(float f) {
  unsigned u = __float_as_uint(f);
  unsigned r = (u + 0x7FFFu + ((u >> 16) & 1u)) >> 16;
  return (u16)r;
}

// ---------------- fp32 -> bf16 cast (vectorized) ----------------
__global__ __launch_bounds__(256) void cast_bf16(const float* __restrict__ in,
                                                 u16* __restrict__ out) {
  int i = (blockIdx.x * 256 + threadIdx.x) * 4;
  float4 v = *(const float4*)(in + i);
  ushort4 o;
  o.x = f2b(v.x); o.y = f2b(v.y); o.z = f2b(v.z); o.w = f2b(v.w);
  *(ushort4*)(out + i) = o;
}

// ---------------- DCT-I matrix builders (bf16) ----------------
__global__ __launch_bounds__(256) void build_M1(u16* __restrict__ M1) {
  int idx = blockIdx.x * 256 + threadIdx.x;
  int k = idx >> 11, n = idx & 2047;
  int r = (k * n) % (2 * (NG - 1));
  float ang = (float)r * (3.14159265358979323846f / (NG - 1));
  float v = __cosf(ang) * ((n == 0 || n == NG - 1) ? 1.0f : 2.0f);
  M1[idx] = f2b(v);
}

__global__ __launch_bounds__(256) void build_M3(u16* __restrict__ M3) {
  int idx = blockIdx.x * 256 + threadIdx.x;
  int n = idx >> 9, k = idx & 511;
  int r = (n * k) % (2 * (NG - 1));
  float ang = (float)r * (3.14159265358979323846f / (NG - 1));
  float v = __cosf(ang) * ((k == 0) ? 1.0f : 2.0f);
  M3[idx] = f2b(v);
}

// ---------------- bf16 MFMA GEMM, Bt form: C[m][n] = sum_k A[m][k]*Bt[n][k] ----
// 256 threads = 4 waves (2x2); wave computes (MI*16)x(NI*16).
// Tile TM=MI*32, TN=NI*32, BK=64. LDS rows padded +8 u16 (stride 144 B = 36
// banks): fragment reads 2-way (free), staging writes conflict-free.
template<int MI, int NI>
__global__ __launch_bounds__(256, 2) void gemm_bt(
    const u16* __restrict__ A,   // [M][K] bf16
    const u16* __restrict__ Bt,  // [N][K] bf16
    float* __restrict__ C,       // [M][N] fp32
    int K, int N) {
  constexpr int TM = MI * 32;
  constexpr int TN = NI * 32;
  constexpr int BK = 64;
  constexpr int PK = BK + 8;     // pad: 144 B row stride (16B-aligned, 36 banks)
  __shared__ u16 As[TM][PK];
  __shared__ u16 Bs[TN][PK];

  const int tid  = threadIdx.x;
  const int lane = tid & 63;
  const int wave = tid >> 6;
  const int wm = (wave >> 1) * (MI * 16);
  const int wn = (wave & 1) * (NI * 16);
  const long bm = (long)blockIdx.y * TM;
  const long bn = (long)blockIdx.x * TN;

  const int lrow = lane & 15;
  const int lko  = (lane >> 4) * 8;

  const int srow = tid >> 3;           // 0..31
  const int scol = (tid & 7) * 8;      // 0,8,...,56

  f32x4 acc[MI][NI] = {};

  const u16* Ap = A  + (bm + srow) * (long)K + scol;
  const u16* Bp = Bt + (bn + srow) * (long)K + scol;

  for (int k0 = 0; k0 < K; k0 += BK) {
#pragma unroll
    for (int r = 0; r < TM / 32; ++r)
      *(uint4*)&As[srow + r * 32][scol] = *(const uint4*)(Ap + (long)r * 32 * K + k0);
#pragma unroll
    for (int r = 0; r < TN / 32; ++r)
      *(uint4*)&Bs[srow + r * 32][scol] = *(const uint4*)(Bp + (long)r * 32 * K + k0);
    __syncthreads();

#pragma unroll
    for (int kk = 0; kk < BK; kk += 32) {
      short8 af[MI], bfr[NI];
#pragma unroll
      for (int i = 0; i < MI; ++i)
        af[i] = *(const short8*)&As[wm + i * 16 + lrow][kk + lko];
#pragma unroll
      for (int j = 0; j < NI; ++j)
        bfr[j] = *(const short8*)&Bs[wn + j * 16 + lrow][kk + lko];
#pragma unroll
      for (int i = 0; i < MI; ++i)
#pragma unroll
        for (int j = 0; j < NI; ++j)
          acc[i][j] = __builtin_amdgcn_mfma_f32_16x16x32_bf16(af[i], bfr[j], acc[i][j], 0, 0, 0);
    }
    __syncthreads();
  }

  const int crow = (lane >> 4) * 4;
  const int ccol = lane & 15;
#pragma unroll
  for (int i = 0; i < MI; ++i)
#pragma unroll
    for (int j = 0; j < NI; ++j) {
      long gm = bm + wm + i * 16 + crow;
      long gn = bn + wn + j * 16 + ccol;
      float* cp = C + gm * (long)N + gn;
#pragma unroll
      for (int r = 0; r < 4; ++r)
        cp[(long)r * N] = acc[i][j][r];
    }
}

// ---------------- fp32 transpose: w [4096][512] -> wT [512][4096] -------------
__global__ __launch_bounds__(256) void transpose_w(const float* __restrict__ w,
                                                   float* __restrict__ wT) {
  __shared__ float S[64][65];
  const int ib = blockIdx.x;   // idx tile (64)
  const int kb = blockIdx.y;   // k tile (8)
  const int t = threadIdx.x;
  const int r0 = t >> 6;
  const int c  = t & 63;
#pragma unroll
  for (int j = 0; j < 16; ++j) {
    int r = r0 + j * 4;
    S[r][c] = w[(size_t)(ib * 64 + r) * MD + kb * 64 + c];
  }
  __syncthreads();
#pragma unroll
  for (int j = 0; j < 16; ++j) {
    int r = r0 + j * 4;
    wT[(size_t)(kb * 64 + r) * 4096 + ib * 64 + c] = S[c][r];
  }
}

// ---------------- per-mode 64x64x64 mix (coalesced wT) ----------------
__global__ __launch_bounds__(256, 4) void mode_mix(
    const float* __restrict__ xcT,   // [MD][B_*IC] fp32
    const float* __restrict__ wT,    // [MD][IC*OC] fp32
    u16* __restrict__ omT) {         // [MD][B_*OC] bf16
  __shared__ float Lxc[4096];        // [b*64+i]
  __shared__ float Lw[4096];         // [i*64+o]
  const int k = blockIdx.x;
  const int t = threadIdx.x;
#pragma unroll
  for (int j = 0; j < 16; ++j) {
    int idx = t + j * 256;
    Lxc[idx] = xcT[(size_t)k * 4096 + idx];
    Lw[idx]  = wT[(size_t)k * 4096 + idx];
  }
  __syncthreads();

  const int b0 = (t >> 4) << 2;
  const int o0 = (t & 15) << 2;
  float acc[4][4] = {};
  for (int i = 0; i < 64; ++i) {
    float xv0 = Lxc[(b0 + 0) * 64 + i];
    float xv1 = Lxc[(b0 + 1) * 64 + i];
    float xv2 = Lxc[(b0 + 2) * 64 + i];
    float xv3 = Lxc[(b0 + 3) * 64 + i];
    float4 wv = *(const float4*)&Lw[i * 64 + o0];
    acc[0][0] += xv0 * wv.x; acc[0][1] += xv0 * wv.y; acc[0][2] += xv0 * wv.z; acc[0][3] += xv0 * wv.w;
    acc[1][0] += xv1 * wv.x; acc[1][1] += xv1 * wv.y; acc[1][2] += xv1 * wv.z; acc[1][3] += xv1 * wv.w;
    acc[2][0] += xv2 * wv.x; acc[2][1] += xv2 * wv.y; acc[2][2] += xv2 * wv.z; acc[2][3] += xv2 * wv.w;
    acc[3][0] += xv3 * wv.x; acc[3][1] += xv3 * wv.y; acc[3][2] += xv3 * wv.z; acc[3][3] += xv3 * wv.w;
  }
#pragma unroll
  for (int r = 0; r < 4; ++r) {
    ushort4 p;
    p.x = f2b(acc[r][0]); p.y = f2b(acc[r][1]); p.z = f2b(acc[r][2]); p.w = f2b(acc[r][3]);
    *(ushort4*)&omT[(size_t)k * 4096 + (b0 + r) * 64 + o0] = p;
  }
}

// ---------------- bf16 transpose: omT [MD][4096] -> om [4096][MD] -------------
__global__ __launch_bounds__(256) void transpose_om(const u16* __restrict__ omT,
                                                    u16* __restrict__ om) {
  __shared__ u16 S[64][65];
  const int bb = blockIdx.x;
  const int kb = blockIdx.y;
  const int t = threadIdx.x;
  const int r0 = t >> 6;
  const int c  = t & 63;
#pragma unroll
  for (int j = 0; j < 16; ++j) {
    int kr = r0 + j * 4;
    S[kr][c] = omT[(size_t)(kb * 64 + kr) * 4096 + bb * 64 + c];
  }
  __syncthreads();
#pragma unroll
  for (int j = 0; j < 16; ++j) {
    int br = r0 + j * 4;
    om[(size_t)(bb * 64 + br) * MD + kb * 64 + c] = S[c][br];
  }
}

extern "C" void kernel_launch(void* const* d_in, const int* in_sizes, int n_in,
                              void* d_out, int out_size, void* d_ws, size_t ws_size,
                              hipStream_t stream) {
  const float* x = (const float*)d_in[0];   // [B_][IC][NG]
  const float* w = (const float*)d_in[1];   // [IC][OC][MD]
  float* out = (float*)d_out;               // [B_][OC][NG]

  // ws layout (28 MB total, region reuse):
  //  [0,16M):  xb (bf16 x) during G1; after G1: wT(8M) | omT(4M) | om(4M)
  //  [16M,18M): M1   [18M,20M): M3   [20M,28M): xcT (fp32)
  char* ws = (char*)d_ws;
  u16*   xb  = (u16*)ws;
  float* wT  = (float*)ws;
  u16*   omT = (u16*)(ws + (size_t)8 * 1024 * 1024);
  u16*   om  = (u16*)(ws + (size_t)12 * 1024 * 1024);
  u16*   M1  = (u16*)(ws + (size_t)16 * 1024 * 1024);
  u16*   M3  = (u16*)(ws + (size_t)18 * 1024 * 1024);
  float* xcT = (float*)(ws + (size_t)20 * 1024 * 1024);

  cast_bf16<<<(B_ * IC * NG / 4) / 256, 256, 0, stream>>>(x, xb);
  build_M1<<<(MD * NG) / 256, 256, 0, stream>>>(M1);
  build_M3<<<(NG * MD) / 256, 256, 0, stream>>>(M3);

  // G1: xcT[512][4096] = M1[512][2048] * xb[4096][2048]^T  (K=2048)
  // tile 64x128 -> grid 32x8 = 256 blocks
  gemm_bt<2, 4><<<dim3((B_ * IC) / 128, MD / 64), 256, 0, stream>>>(M1, xb, xcT, NG, B_ * IC);

  // w transpose into dead xb region
  transpose_w<<<dim3(64, 8), 256, 0, stream>>>(w, wT);

  // mode mix: omT[512][4096]
  mode_mix<<<MD, 256, 0, stream>>>(xcT, wT, omT);

  // transpose to om[4096][512]
  transpose_om<<<dim3((B_ * OC) / 64, MD / 64), 256, 0, stream>>>(omT, om);

  // G3: out[4096][2048] = om[4096][512] * M3[2048][512]^T  (K=512)
  gemm_bt<4, 4><<<dim3(NG / 128, (B_ * OC) / 128), 256, 0, stream>>>(om, M3, out, MD, NG);
}

// Round 3
// 146.522 us; speedup vs baseline: 1.3571x; 1.3571x over previous
//
#include <hip/hip_runtime.h>

typedef unsigned short u16;
typedef __attribute__((ext_vector_type(8))) short short8;
typedef __attribute__((ext_vector_type(4))) float f32x4;

#define B_  64
#define IC  64
#define OC  64
#define NG  2048
#define MD  512

__device__ inline u16 f2b(float f) {
  unsigned u = __float_as_uint(f);
  unsigned r = (u + 0x7FFFu + ((u >> 16) & 1u)) >> 16;
  return (u16)r;
}

// async global->LDS, 16 B per lane. LDS dest is wave-uniform base + lane*16.
__device__ __forceinline__ void gld_lds16(const u16* g, const u16* l) {
  __builtin_amdgcn_global_load_lds(
      (__attribute__((address_space(1))) void*)(uintptr_t)(g),
      (__attribute__((address_space(3))) void*)(unsigned)(uintptr_t)(l),
      16, 0, 0);
}

// ---------------- fp32 -> bf16 cast (vectorized) ----------------
__global__ __launch_bounds__(256) void cast_bf16(const float* __restrict__ in,
                                                 u16* __restrict__ out) {
  int i = (blockIdx.x * 256 + threadIdx.x) * 4;
  float4 v = *(const float4*)(in + i);
  ushort4 o;
  o.x = f2b(v.x); o.y = f2b(v.y); o.z = f2b(v.z); o.w = f2b(v.w);
  *(ushort4*)(out + i) = o;
}

// ---------------- DCT-I matrix builders (bf16) ----------------
__global__ __launch_bounds__(256) void build_M1(u16* __restrict__ M1) {
  int idx = blockIdx.x * 256 + threadIdx.x;
  int k = idx >> 11, n = idx & 2047;
  int r = (k * n) % (2 * (NG - 1));
  float ang = (float)r * (3.14159265358979323846f / (NG - 1));
  float v = __cosf(ang) * ((n == 0 || n == NG - 1) ? 1.0f : 2.0f);
  M1[idx] = f2b(v);
}

__global__ __launch_bounds__(256) void build_M3(u16* __restrict__ M3) {
  int idx = blockIdx.x * 256 + threadIdx.x;
  int n = idx >> 9, k = idx & 511;
  int r = (n * k) % (2 * (NG - 1));
  float ang = (float)r * (3.14159265358979323846f / (NG - 1));
  float v = __cosf(ang) * ((k == 0) ? 1.0f : 2.0f);
  M3[idx] = f2b(v);
}

// ---------------- bf16 MFMA GEMM, Bt form, async LDS staging ----------------
// C[m][n] = sum_k A[m][k]*Bt[n][k].  256 thr = 4 waves (2x2), wave = (MI*16)x(NI*16).
// TM=MI*32, TN=NI*32, BK=64. S holds As rows [0,TM) then Bs rows [TM,TM+TN),
// 64 u16 per row, XOR-swizzled: physical chunk = logical chunk ^ (row&7).
// Staging lane i of an 8-row issue writes phys (row0+i/8, chunk i&7) so its
// global source chunk is (i&7)^(i/8) — constant per lane. Frag ds_read_b128s
// then hit all 32 banks (conflict-free, no padding needed).
template<int MI, int NI>
__global__ __launch_bounds__(256, 2) void gemm_bt2(
    const u16* __restrict__ A,   // [M][K] bf16
    const u16* __restrict__ Bt,  // [N][K] bf16
    float* __restrict__ C,       // [M][N] fp32
    int K, int N) {
  constexpr int TM = MI * 32;
  constexpr int TN = NI * 32;
  constexpr int BK = 64;
  constexpr int ROWS = TM + TN;
  constexpr int CH = ROWS / 4;      // staged rows per wave
  constexpr int NISSUE = CH / 8;    // 8 rows (1 KB) per issue
  __shared__ u16 S[ROWS * BK];

  const int tid  = threadIdx.x;
  const int lane = tid & 63;
  const int wave = tid >> 6;
  const int wm = (wave >> 1) * (MI * 16);
  const int wn = (wave & 1) * (NI * 16);
  const long bm = (long)blockIdx.y * TM;
  const long bn = (long)blockIdx.x * TN;

  const int lrow = lane & 15;
  const int lhi  = lane >> 4;       // 0..3

  // staging source: swizzled col chunk, constant per lane
  const int scc = (((lane & 7) ^ (lane >> 3)) * 8);
  const int r0 = wave * CH;

  const u16* gsrc[NISSUE];
  const u16* ldst[NISSUE];
#pragma unroll
  for (int ii = 0; ii < NISSUE; ++ii) {
    int rr = r0 + ii * 8 + (lane >> 3);
    gsrc[ii] = (rr < TM) ? (A + (bm + rr) * (long)K + scc)
                         : (Bt + (bn + rr - TM) * (long)K + scc);
    ldst[ii] = &S[(r0 + ii * 8) * BK];
  }

  f32x4 acc[MI][NI] = {};

  for (int k0 = 0; k0 < K; k0 += BK) {
#pragma unroll
    for (int ii = 0; ii < NISSUE; ++ii)
      gld_lds16(gsrc[ii] + k0, ldst[ii]);
    __syncthreads();   // drains vmcnt: staged data visible to all waves

#pragma unroll
    for (int kk8 = 0; kk8 < 8; kk8 += 4) {   // logical chunk base: kk/8
      short8 af[MI], bfr[NI];
#pragma unroll
      for (int i = 0; i < MI; ++i) {
        int pch = ((kk8 + lhi) ^ (lane & 7));
        af[i] = *(const short8*)&S[(wm + i * 16 + lrow) * BK + pch * 8];
      }
#pragma unroll
      for (int j = 0; j < NI; ++j) {
        int pch = ((kk8 + lhi) ^ (lane & 7));
        bfr[j] = *(const short8*)&S[(TM + wn + j * 16 + lrow) * BK + pch * 8];
      }
#pragma unroll
      for (int i = 0; i < MI; ++i)
#pragma unroll
        for (int j = 0; j < NI; ++j)
          acc[i][j] = __builtin_amdgcn_mfma_f32_16x16x32_bf16(af[i], bfr[j], acc[i][j], 0, 0, 0);
    }
    __syncthreads();   // protect S from next iteration's staging
  }

  const int crow = (lane >> 4) * 4;
  const int ccol = lane & 15;
#pragma unroll
  for (int i = 0; i < MI; ++i)
#pragma unroll
    for (int j = 0; j < NI; ++j) {
      long gm = bm + wm + i * 16 + crow;
      long gn = bn + wn + j * 16 + ccol;
      float* cp = C + gm * (long)N + gn;
#pragma unroll
      for (int r = 0; r < 4; ++r)
        cp[(long)r * N] = acc[i][j][r];
    }
}

// ---------------- fp32 transpose: w [4096][512] -> wT [512][4096] -------------
__global__ __launch_bounds__(256) void transpose_w(const float* __restrict__ w,
                                                   float* __restrict__ wT) {
  __shared__ float S[64][65];
  const int ib = blockIdx.x;
  const int kb = blockIdx.y;
  const int t = threadIdx.x;
  const int r0 = t >> 6;
  const int c  = t & 63;
#pragma unroll
  for (int j = 0; j < 16; ++j) {
    int r = r0 + j * 4;
    S[r][c] = w[(size_t)(ib * 64 + r) * MD + kb * 64 + c];
  }
  __syncthreads();
#pragma unroll
  for (int j = 0; j < 16; ++j) {
    int r = r0 + j * 4;
    wT[(size_t)(kb * 64 + r) * 4096 + ib * 64 + c] = S[c][r];
  }
}

// ---------------- per-mode 64x64x64 mix (coalesced wT) ----------------
__global__ __launch_bounds__(256, 4) void mode_mix(
    const float* __restrict__ xcT,   // [MD][B_*IC] fp32
    const float* __restrict__ wT,    // [MD][IC*OC] fp32
    u16* __restrict__ omT) {         // [MD][B_*OC] bf16
  __shared__ float Lxc[4096];
  __shared__ float Lw[4096];
  const int k = blockIdx.x;
  const int t = threadIdx.x;
#pragma unroll
  for (int j = 0; j < 16; ++j) {
    int idx = t + j * 256;
    Lxc[idx] = xcT[(size_t)k * 4096 + idx];
    Lw[idx]  = wT[(size_t)k * 4096 + idx];
  }
  __syncthreads();

  const int b0 = (t >> 4) << 2;
  const int o0 = (t & 15) << 2;
  float acc[4][4] = {};
  for (int i = 0; i < 64; ++i) {
    float xv0 = Lxc[(b0 + 0) * 64 + i];
    float xv1 = Lxc[(b0 + 1) * 64 + i];
    float xv2 = Lxc[(b0 + 2) * 64 + i];
    float xv3 = Lxc[(b0 + 3) * 64 + i];
    float4 wv = *(const float4*)&Lw[i * 64 + o0];
    acc[0][0] += xv0 * wv.x; acc[0][1] += xv0 * wv.y; acc[0][2] += xv0 * wv.z; acc[0][3] += xv0 * wv.w;
    acc[1][0] += xv1 * wv.x; acc[1][1] += xv1 * wv.y; acc[1][2] += xv1 * wv.z; acc[1][3] += xv1 * wv.w;
    acc[2][0] += xv2 * wv.x; acc[2][1] += xv2 * wv.y; acc[2][2] += xv2 * wv.z; acc[2][3] += xv2 * wv.w;
    acc[3][0] += xv3 * wv.x; acc[3][1] += xv3 * wv.y; acc[3][2] += xv3 * wv.z; acc[3][3] += xv3 * wv.w;
  }
#pragma unroll
  for (int r = 0; r < 4; ++r) {
    ushort4 p;
    p.x = f2b(acc[r][0]); p.y = f2b(acc[r][1]); p.z = f2b(acc[r][2]); p.w = f2b(acc[r][3]);
    *(ushort4*)&omT[(size_t)k * 4096 + (b0 + r) * 64 + o0] = p;
  }
}

// ---------------- bf16 transpose: omT [MD][4096] -> om [4096][MD] -------------
__global__ __launch_bounds__(256) void transpose_om(const u16* __restrict__ omT,
                                                    u16* __restrict__ om) {
  __shared__ u16 S[64][65];
  const int bb = blockIdx.x;
  const int kb = blockIdx.y;
  const int t = threadIdx.x;
  const int r0 = t >> 6;
  const int c  = t & 63;
#pragma unroll
  for (int j = 0; j < 16; ++j) {
    int kr = r0 + j * 4;
    S[kr][c] = omT[(size_t)(kb * 64 + kr) * 4096 + bb * 64 + c];
  }
  __syncthreads();
#pragma unroll
  for (int j = 0; j < 16; ++j) {
    int br = r0 + j * 4;
    om[(size_t)(bb * 64 + br) * MD + kb * 64 + c] = S[c][br];
  }
}

extern "C" void kernel_launch(void* const* d_in, const int* in_sizes, int n_in,
                              void* d_out, int out_size, void* d_ws, size_t ws_size,
                              hipStream_t stream) {
  const float* x = (const float*)d_in[0];   // [B_][IC][NG]
  const float* w = (const float*)d_in[1];   // [IC][OC][MD]
  float* out = (float*)d_out;               // [B_][OC][NG]

  // ws layout (28 MB, region reuse):
  //  [0,16M):  xb (bf16 x) during G1; after G1: wT(8M) | omT(4M) | om(4M)
  //  [16M,18M): M1   [18M,20M): M3   [20M,28M): xcT (fp32)
  char* ws = (char*)d_ws;
  u16*   xb  = (u16*)ws;
  float* wT  = (float*)ws;
  u16*   omT = (u16*)(ws + (size_t)8 * 1024 * 1024);
  u16*   om  = (u16*)(ws + (size_t)12 * 1024 * 1024);
  u16*   M1  = (u16*)(ws + (size_t)16 * 1024 * 1024);
  u16*   M3  = (u16*)(ws + (size_t)18 * 1024 * 1024);
  float* xcT = (float*)(ws + (size_t)20 * 1024 * 1024);

  cast_bf16<<<(B_ * IC * NG / 4) / 256, 256, 0, stream>>>(x, xb);
  build_M1<<<(MD * NG) / 256, 256, 0, stream>>>(M1);
  build_M3<<<(NG * MD) / 256, 256, 0, stream>>>(M3);

  // G1: xcT[512][4096] = M1[512][2048] * xb[4096][2048]^T  (K=2048)
  // 64x64 tiles -> grid 64x8 = 512 blocks (2 blocks/CU)
  gemm_bt2<2, 2><<<dim3((B_ * IC) / 64, MD / 64), 256, 0, stream>>>(M1, xb, xcT, NG, B_ * IC);

  // w transpose into dead xb region
  transpose_w<<<dim3(64, 8), 256, 0, stream>>>(w, wT);

  // mode mix: omT[512][4096]
  mode_mix<<<MD, 256, 0, stream>>>(xcT, wT, omT);

  // transpose to om[4096][512]
  transpose_om<<<dim3((B_ * OC) / 64, MD / 64), 256, 0, stream>>>(omT, om);

  // G3: out[4096][2048] = om[4096][512] * M3[2048][512]^T  (K=512)
  // 128x128 tiles -> grid 16x32 = 512 blocks
  gemm_bt2<4, 4><<<dim3(NG / 128, (B_ * OC) / 128), 256, 0, stream>>>(om, M3, out, MD, NG);
}

// Round 4
// 133.085 us; speedup vs baseline: 1.4942x; 1.1010x over previous
//
#include <hip/hip_runtime.h>

typedef unsigned short u16;
typedef __attribute__((ext_vector_type(8))) short short8;
typedef __attribute__((ext_vector_type(4))) float f32x4;

#define B_  64
#define IC  64
#define OC  64
#define NG  2048
#define MD  512

__device__ inline u16 f2b(float f) {
  unsigned u = __float_as_uint(f);
  unsigned r = (u + 0x7FFFu + ((u >> 16) & 1u)) >> 16;
  return (u16)r;
}

// async global->LDS, 16 B per lane. LDS dest is wave-uniform base + lane*16.
__device__ __forceinline__ void gld_lds16(const u16* g, const u16* l) {
  __builtin_amdgcn_global_load_lds(
      (__attribute__((address_space(1))) void*)(uintptr_t)(g),
      (__attribute__((address_space(3))) void*)(unsigned)(uintptr_t)(l),
      16, 0, 0);
}

// ================= fused prologue =================
// grid partition: [0,8192) cast x->bf16 | [8192,8704) w->wT2 bf16
//                 [8704,12800) build M1 | [12800,16896) build M3
__global__ __launch_bounds__(256) void prep(
    const float* __restrict__ x, const float* __restrict__ w,
    u16* __restrict__ xb, u16* __restrict__ wT2,
    u16* __restrict__ M1, u16* __restrict__ M3) {
  __shared__ float S[64][65];
  const int id = blockIdx.x;
  const int t = threadIdx.x;
  if (id < 8192) {                      // ---- cast x (8M floats) ----
    int i = (id * 256 + t) * 4;
    float4 v = *(const float4*)(x + i);
    ushort4 o;
    o.x = f2b(v.x); o.y = f2b(v.y); o.z = f2b(v.z); o.w = f2b(v.w);
    *(ushort4*)(xb + i) = o;
  } else if (id < 8704) {               // ---- wT2[k][o*64+i] = w[i][o][k] ----
    int wb = id - 8192;
    int o = wb & 63, kb = wb >> 6;      // o: 0..63, kb: 0..7
    int r0 = t >> 6, c = t & 63;
#pragma unroll
    for (int j = 0; j < 16; ++j) {
      int i = r0 + j * 4;
      S[i][c] = w[(size_t)(i * 64 + o) * MD + kb * 64 + c];
    }
    __syncthreads();
#pragma unroll
    for (int j = 0; j < 16; ++j) {
      int kk = r0 + j * 4;
      wT2[(size_t)(kb * 64 + kk) * 4096 + o * 64 + c] = f2b(S[c][kk]);
    }
  } else if (id < 12800) {              // ---- M1[k][n], [MD][NG] ----
    int idx = (id - 8704) * 256 + t;
    int k = idx >> 11, n = idx & 2047;
    int r = (k * n) % (2 * (NG - 1));
    float ang = (float)r * (3.14159265358979323846f / (NG - 1));
    float v = __cosf(ang) * ((n == 0 || n == NG - 1) ? 1.0f : 2.0f);
    M1[idx] = f2b(v);
  } else {                              // ---- M3[n][k], [NG][MD] ----
    int idx = (id - 12800) * 256 + t;
    int n = idx >> 9, k = idx & 511;
    int r = (n * k) % (2 * (NG - 1));
    float ang = (float)r * (3.14159265358979323846f / (NG - 1));
    float v = __cosf(ang) * ((k == 0) ? 1.0f : 2.0f);
    M3[idx] = f2b(v);
  }
}

// ================= bf16 MFMA GEMM, Bt form, async LDS staging =================
// C[m][n] = sum_k A[m][k]*Bt[n][k].  256 thr = 4 waves (2x2), wave (MI*16)x(NI*16).
// TM=MI*32, TN=NI*32, BK=64. XOR swizzle: physical chunk = logical chunk ^ (row&7).
template<int MI, int NI, bool OUT_BF16>
__global__ __launch_bounds__(256, 2) void gemm_bt2(
    const u16* __restrict__ A,   // [M][K] bf16
    const u16* __restrict__ Bt,  // [N][K] bf16
    void* __restrict__ Cv,       // [M][N] fp32 or bf16
    int K, int N) {
  constexpr int TM = MI * 32;
  constexpr int TN = NI * 32;
  constexpr int BK = 64;
  constexpr int ROWS = TM + TN;
  constexpr int CH = ROWS / 4;
  constexpr int NISSUE = CH / 8;
  __shared__ u16 S[ROWS * BK];

  const int tid  = threadIdx.x;
  const int lane = tid & 63;
  const int wave = tid >> 6;
  const int wm = (wave >> 1) * (MI * 16);
  const int wn = (wave & 1) * (NI * 16);
  const long bm = (long)blockIdx.y * TM;
  const long bn = (long)blockIdx.x * TN;

  const int lrow = lane & 15;
  const int lhi  = lane >> 4;

  const int scc = (((lane & 7) ^ (lane >> 3)) * 8);
  const int r0 = wave * CH;

  const u16* gsrc[NISSUE];
  const u16* ldst[NISSUE];
#pragma unroll
  for (int ii = 0; ii < NISSUE; ++ii) {
    int rr = r0 + ii * 8 + (lane >> 3);
    gsrc[ii] = (rr < TM) ? (A + (bm + rr) * (long)K + scc)
                         : (Bt + (bn + rr - TM) * (long)K + scc);
    ldst[ii] = &S[(r0 + ii * 8) * BK];
  }

  f32x4 acc[MI][NI] = {};

  for (int k0 = 0; k0 < K; k0 += BK) {
#pragma unroll
    for (int ii = 0; ii < NISSUE; ++ii)
      gld_lds16(gsrc[ii] + k0, ldst[ii]);
    __syncthreads();

#pragma unroll
    for (int kk8 = 0; kk8 < 8; kk8 += 4) {
      short8 af[MI], bfr[NI];
#pragma unroll
      for (int i = 0; i < MI; ++i) {
        int pch = ((kk8 + lhi) ^ (lane & 7));
        af[i] = *(const short8*)&S[(wm + i * 16 + lrow) * BK + pch * 8];
      }
#pragma unroll
      for (int j = 0; j < NI; ++j) {
        int pch = ((kk8 + lhi) ^ (lane & 7));
        bfr[j] = *(const short8*)&S[(TM + wn + j * 16 + lrow) * BK + pch * 8];
      }
#pragma unroll
      for (int i = 0; i < MI; ++i)
#pragma unroll
        for (int j = 0; j < NI; ++j)
          acc[i][j] = __builtin_amdgcn_mfma_f32_16x16x32_bf16(af[i], bfr[j], acc[i][j], 0, 0, 0);
    }
    __syncthreads();
  }

  const int crow = (lane >> 4) * 4;
  const int ccol = lane & 15;
#pragma unroll
  for (int i = 0; i < MI; ++i)
#pragma unroll
    for (int j = 0; j < NI; ++j) {
      long gm = bm + wm + i * 16 + crow;
      long gn = bn + wn + j * 16 + ccol;
      if (OUT_BF16) {
        u16* cp = (u16*)Cv + gm * (long)N + gn;
#pragma unroll
        for (int r = 0; r < 4; ++r)
          cp[(long)r * N] = f2b(acc[i][j][r]);
      } else {
        float* cp = (float*)Cv + gm * (long)N + gn;
#pragma unroll
        for (int r = 0; r < 4; ++r)
          cp[(long)r * N] = acc[i][j][r];
      }
    }
}

// ================= per-mode 64x64x64 mix via MFMA =================
// omT[k][b*64+o] = sum_i xcT[k][b*64+i] * wT2[k][o*64+i]
// LDS rows padded to 72 u16 (144 B): frag reads 2-way (free).
__global__ __launch_bounds__(256, 4) void mode_mix_mfma(
    const u16* __restrict__ xcT,   // [MD][4096] bf16
    const u16* __restrict__ wT2,   // [MD][4096] bf16 (o*64+i order)
    u16* __restrict__ omT) {       // [MD][4096] bf16
  constexpr int PK = 72;
  __shared__ u16 S[128 * PK];      // rows 0-63: xc[b][i], 64-127: w[o][i]
  const int k = blockIdx.x;
  const int t = threadIdx.x;

#pragma unroll
  for (int c = 0; c < 4; ++c) {
    int ch = t + c * 256;          // 0..1023 chunks of 8 bf16
    int half = ch >> 9, cc = ch & 511;
    int row = cc >> 3, col8 = cc & 7;
    const u16* src = half ? wT2 : xcT;
    uint4 v = *(const uint4*)(src + (size_t)k * 4096 + row * 64 + col8 * 8);
    *(uint4*)&S[(half * 64 + row) * PK + col8 * 8] = v;
  }
  __syncthreads();

  const int lane = t & 63;
  const int wave = t >> 6;
  const int wm = (wave >> 1) * 32;
  const int wn = (wave & 1) * 32;
  const int lrow = lane & 15;
  const int lhi  = lane >> 4;

  f32x4 acc[2][2] = {};
#pragma unroll
  for (int kk8 = 0; kk8 < 8; kk8 += 4) {
    short8 af[2], bfr[2];
#pragma unroll
    for (int i = 0; i < 2; ++i)
      af[i] = *(const short8*)&S[(wm + i * 16 + lrow) * PK + (kk8 + lhi) * 8];
#pragma unroll
    for (int j = 0; j < 2; ++j)
      bfr[j] = *(const short8*)&S[(64 + wn + j * 16 + lrow) * PK + (kk8 + lhi) * 8];
#pragma unroll
    for (int i = 0; i < 2; ++i)
#pragma unroll
      for (int j = 0; j < 2; ++j)
        acc[i][j] = __builtin_amdgcn_mfma_f32_16x16x32_bf16(af[i], bfr[j], acc[i][j], 0, 0, 0);
  }

  const int crow = (lane >> 4) * 4;
  const int ccol = lane & 15;
#pragma unroll
  for (int i = 0; i < 2; ++i)
#pragma unroll
    for (int j = 0; j < 2; ++j) {
      int b = wm + i * 16 + crow;
      int o = wn + j * 16 + ccol;
#pragma unroll
      for (int r = 0; r < 4; ++r)
        omT[(size_t)k * 4096 + (b + r) * 64 + o] = f2b(acc[i][j][r]);
    }
}

// ================= bf16 transpose: omT [MD][4096] -> om [4096][MD] =============
__global__ __launch_bounds__(256) void transpose_om(const u16* __restrict__ omT,
                                                    u16* __restrict__ om) {
  __shared__ u16 S[64][65];
  const int bb = blockIdx.x;
  const int kb = blockIdx.y;
  const int t = threadIdx.x;
  const int r0 = t >> 6;
  const int c  = t & 63;
#pragma unroll
  for (int j = 0; j < 16; ++j) {
    int kr = r0 + j * 4;
    S[kr][c] = omT[(size_t)(kb * 64 + kr) * 4096 + bb * 64 + c];
  }
  __syncthreads();
#pragma unroll
  for (int j = 0; j < 16; ++j) {
    int br = r0 + j * 4;
    om[(size_t)(bb * 64 + br) * MD + kb * 64 + c] = S[c][br];
  }
}

extern "C" void kernel_launch(void* const* d_in, const int* in_sizes, int n_in,
                              void* d_out, int out_size, void* d_ws, size_t ws_size,
                              hipStream_t stream) {
  const float* x = (const float*)d_in[0];   // [B_][IC][NG]
  const float* w = (const float*)d_in[1];   // [IC][OC][MD]
  float* out = (float*)d_out;               // [B_][OC][NG]

  // ws layout (36 MB, no reuse):
  //  [0,16M): xb bf16 | [16,18): M1 | [18,20): M3 | [20,24): xcT bf16
  //  [24,28): wT2 bf16 | [28,32): omT bf16 | [32,36): om bf16
  char* ws = (char*)d_ws;
  u16* xb  = (u16*)ws;
  u16* M1  = (u16*)(ws + (size_t)16 * 1024 * 1024);
  u16* M3  = (u16*)(ws + (size_t)18 * 1024 * 1024);
  u16* xcT = (u16*)(ws + (size_t)20 * 1024 * 1024);
  u16* wT2 = (u16*)(ws + (size_t)24 * 1024 * 1024);
  u16* omT = (u16*)(ws + (size_t)28 * 1024 * 1024);
  u16* om  = (u16*)(ws + (size_t)32 * 1024 * 1024);

  // fused prologue: cast + w-transpose + M1 + M3
  prep<<<16896, 256, 0, stream>>>(x, w, xb, wT2, M1, M3);

  // G1: xcT[512][4096] = M1[512][2048] * xb[4096][2048]^T  (K=2048), bf16 out
  gemm_bt2<2, 2, true><<<dim3((B_ * IC) / 64, MD / 64), 256, 0, stream>>>(
      M1, xb, xcT, NG, B_ * IC);

  // per-mode MFMA mix: omT[512][4096]
  mode_mix_mfma<<<MD, 256, 0, stream>>>(xcT, wT2, omT);

  // transpose to om[4096][512]
  transpose_om<<<dim3((B_ * OC) / 64, MD / 64), 256, 0, stream>>>(omT, om);

  // G3: out[4096][2048] = om[4096][512] * M3[2048][512]^T  (K=512), fp32 out
  gemm_bt2<4, 4, false><<<dim3(NG / 128, (B_ * OC) / 128), 256, 0, stream>>>(
      om, M3, out, MD, NG);
}

// Round 5
// 129.846 us; speedup vs baseline: 1.5314x; 1.0249x over previous
//
#include <hip/hip_runtime.h>

typedef unsigned short u16;
typedef __attribute__((ext_vector_type(8))) short short8;
typedef __attribute__((ext_vector_type(4))) float f32x4;

#define B_  64
#define IC  64
#define OC  64
#define NG  2048
#define MD  512

__device__ inline u16 f2b(float f) {
  unsigned u = __float_as_uint(f);
  unsigned r = (u + 0x7FFFu + ((u >> 16) & 1u)) >> 16;
  return (u16)r;
}

// async global->LDS, 16 B per lane. LDS dest is wave-uniform base + lane*16.
__device__ __forceinline__ void gld_lds16(const u16* g, const u16* l) {
  __builtin_amdgcn_global_load_lds(
      (__attribute__((address_space(1))) void*)(uintptr_t)(g),
      (__attribute__((address_space(3))) void*)(unsigned)(uintptr_t)(l),
      16, 0, 0);
}

// ================= fused prologue =================
// grid partition: [0,8192) cast x->bf16 | [8192,8704) w->wT2 bf16
//                 [8704,12800) build M1 | [12800,16896) build M3
__global__ __launch_bounds__(256) void prep(
    const float* __restrict__ x, const float* __restrict__ w,
    u16* __restrict__ xb, u16* __restrict__ wT2,
    u16* __restrict__ M1, u16* __restrict__ M3) {
  __shared__ float S[64][65];
  const int id = blockIdx.x;
  const int t = threadIdx.x;
  if (id < 8192) {                      // ---- cast x (8M floats) ----
    int i = (id * 256 + t) * 4;
    float4 v = *(const float4*)(x + i);
    ushort4 o;
    o.x = f2b(v.x); o.y = f2b(v.y); o.z = f2b(v.z); o.w = f2b(v.w);
    *(ushort4*)(xb + i) = o;
  } else if (id < 8704) {               // ---- wT2[k][o*64+i] = w[i][o][k] ----
    int wb = id - 8192;
    int o = wb & 63, kb = wb >> 6;
    int r0 = t >> 6, c = t & 63;
#pragma unroll
    for (int j = 0; j < 16; ++j) {
      int i = r0 + j * 4;
      S[i][c] = w[(size_t)(i * 64 + o) * MD + kb * 64 + c];
    }
    __syncthreads();
#pragma unroll
    for (int j = 0; j < 16; ++j) {
      int kk = r0 + j * 4;
      wT2[(size_t)(kb * 64 + kk) * 4096 + o * 64 + c] = f2b(S[c][kk]);
    }
  } else if (id < 12800) {              // ---- M1[k][n], [MD][NG] ----
    int idx = (id - 8704) * 256 + t;
    int k = idx >> 11, n = idx & 2047;
    int r = (k * n) % (2 * (NG - 1));
    float ang = (float)r * (3.14159265358979323846f / (NG - 1));
    float v = __cosf(ang) * ((n == 0 || n == NG - 1) ? 1.0f : 2.0f);
    M1[idx] = f2b(v);
  } else {                              // ---- M3[n][k], [NG][MD] ----
    int idx = (id - 12800) * 256 + t;
    int n = idx >> 9, k = idx & 511;
    int r = (n * k) % (2 * (NG - 1));
    float ang = (float)r * (3.14159265358979323846f / (NG - 1));
    float v = __cosf(ang) * ((k == 0) ? 1.0f : 2.0f);
    M3[idx] = f2b(v);
  }
}

// ========== bf16 MFMA GEMM, Bt form, double-buffered async staging ==========
// C[m][n] = sum_k A[m][k]*Bt[n][k].  256 thr = 4 waves (2x2), wave (MI*16)x(NI*16).
// TM=MI*32, TN=NI*32, BK=64. XOR swizzle: physical chunk = logical chunk ^ (row&7).
// Single barrier per K-step: prefetch for k+1 issued AFTER the barrier that
// validates buffer p, so its vmcnt drain happens one barrier later — the whole
// compute phase covers the load latency.
template<int MI, int NI, bool OUT_BF16>
__global__ __launch_bounds__(256, 2) void gemm_bt3(
    const u16* __restrict__ A,   // [M][K] bf16
    const u16* __restrict__ Bt,  // [N][K] bf16
    void* __restrict__ Cv,       // [M][N] fp32 or bf16
    int K, int N) {
  constexpr int TM = MI * 32;
  constexpr int TN = NI * 32;
  constexpr int BK = 64;
  constexpr int ROWS = TM + TN;
  constexpr int CH = ROWS / 4;      // rows staged per wave
  constexpr int NISSUE = CH / 8;    // 8 rows (1 KB) per issue
  constexpr int BUF = ROWS * BK;
  __shared__ u16 S[2 * BUF];

  const int tid  = threadIdx.x;
  const int lane = tid & 63;
  const int wave = tid >> 6;
  const int wm = (wave >> 1) * (MI * 16);
  const int wn = (wave & 1) * (NI * 16);
  const long bm = (long)blockIdx.y * TM;
  const long bn = (long)blockIdx.x * TN;

  const int lrow = lane & 15;
  const int lhi  = lane >> 4;

  const int scc = (((lane & 7) ^ (lane >> 3)) * 8);
  const int r0 = wave * CH;

  const u16* gsrc[NISSUE];
  unsigned lofs[NISSUE];
#pragma unroll
  for (int ii = 0; ii < NISSUE; ++ii) {
    int rr = r0 + ii * 8 + (lane >> 3);
    gsrc[ii] = (rr < TM) ? (A + (bm + rr) * (long)K + scc)
                         : (Bt + (bn + rr - TM) * (long)K + scc);
    lofs[ii] = (unsigned)((r0 + ii * 8) * BK);
  }

  f32x4 acc[MI][NI] = {};

  // prologue: stage k0=0 into buffer 0
#pragma unroll
  for (int ii = 0; ii < NISSUE; ++ii)
    gld_lds16(gsrc[ii], &S[lofs[ii]]);

  int p = 0;
  for (int k0 = 0; k0 < K; k0 += BK) {
    __syncthreads();   // drains buffer-p loads (issued one full compute ago)

    if (k0 + BK < K) { // prefetch next into buffer 1-p; stays in flight
#pragma unroll
      for (int ii = 0; ii < NISSUE; ++ii)
        gld_lds16(gsrc[ii] + k0 + BK, &S[(1 - p) * BUF + lofs[ii]]);
    }

    const u16* Sp = &S[p * BUF];
#pragma unroll
    for (int kk8 = 0; kk8 < 8; kk8 += 4) {
      short8 af[MI], bfr[NI];
#pragma unroll
      for (int i = 0; i < MI; ++i) {
        int pch = ((kk8 + lhi) ^ (lane & 7));
        af[i] = *(const short8*)&Sp[(wm + i * 16 + lrow) * BK + pch * 8];
      }
#pragma unroll
      for (int j = 0; j < NI; ++j) {
        int pch = ((kk8 + lhi) ^ (lane & 7));
        bfr[j] = *(const short8*)&Sp[(TM + wn + j * 16 + lrow) * BK + pch * 8];
      }
#pragma unroll
      for (int i = 0; i < MI; ++i)
#pragma unroll
        for (int j = 0; j < NI; ++j)
          acc[i][j] = __builtin_amdgcn_mfma_f32_16x16x32_bf16(af[i], bfr[j], acc[i][j], 0, 0, 0);
    }
    p ^= 1;
  }

  const int crow = (lane >> 4) * 4;
  const int ccol = lane & 15;
#pragma unroll
  for (int i = 0; i < MI; ++i)
#pragma unroll
    for (int j = 0; j < NI; ++j) {
      long gm = bm + wm + i * 16 + crow;
      long gn = bn + wn + j * 16 + ccol;
      if (OUT_BF16) {
        u16* cp = (u16*)Cv + gm * (long)N + gn;
#pragma unroll
        for (int r = 0; r < 4; ++r)
          cp[(long)r * N] = f2b(acc[i][j][r]);
      } else {
        float* cp = (float*)Cv + gm * (long)N + gn;
#pragma unroll
        for (int r = 0; r < 4; ++r)
          cp[(long)r * N] = acc[i][j][r];
      }
    }
}

// ================= per-mode 64x64x64 mix via MFMA =================
// omT[k][b*64+o] = sum_i xcT[k][b*64+i] * wT2[k][o*64+i]
__global__ __launch_bounds__(256, 4) void mode_mix_mfma(
    const u16* __restrict__ xcT,   // [MD][4096] bf16
    const u16* __restrict__ wT2,   // [MD][4096] bf16 (o*64+i order)
    u16* __restrict__ omT) {       // [MD][4096] bf16
  constexpr int PK = 72;
  __shared__ u16 S[128 * PK];      // rows 0-63: xc[b][i], 64-127: w[o][i]
  const int k = blockIdx.x;
  const int t = threadIdx.x;

#pragma unroll
  for (int c = 0; c < 4; ++c) {
    int ch = t + c * 256;
    int half = ch >> 9, cc = ch & 511;
    int row = cc >> 3, col8 = cc & 7;
    const u16* src = half ? wT2 : xcT;
    uint4 v = *(const uint4*)(src + (size_t)k * 4096 + row * 64 + col8 * 8);
    *(uint4*)&S[(half * 64 + row) * PK + col8 * 8] = v;
  }
  __syncthreads();

  const int lane = t & 63;
  const int wave = t >> 6;
  const int wm = (wave >> 1) * 32;
  const int wn = (wave & 1) * 32;
  const int lrow = lane & 15;
  const int lhi  = lane >> 4;

  f32x4 acc[2][2] = {};
#pragma unroll
  for (int kk8 = 0; kk8 < 8; kk8 += 4) {
    short8 af[2], bfr[2];
#pragma unroll
    for (int i = 0; i < 2; ++i)
      af[i] = *(const short8*)&S[(wm + i * 16 + lrow) * PK + (kk8 + lhi) * 8];
#pragma unroll
    for (int j = 0; j < 2; ++j)
      bfr[j] = *(const short8*)&S[(64 + wn + j * 16 + lrow) * PK + (kk8 + lhi) * 8];
#pragma unroll
    for (int i = 0; i < 2; ++i)
#pragma unroll
      for (int j = 0; j < 2; ++j)
        acc[i][j] = __builtin_amdgcn_mfma_f32_16x16x32_bf16(af[i], bfr[j], acc[i][j], 0, 0, 0);
  }

  const int crow = (lane >> 4) * 4;
  const int ccol = lane & 15;
#pragma unroll
  for (int i = 0; i < 2; ++i)
#pragma unroll
    for (int j = 0; j < 2; ++j) {
      int b = wm + i * 16 + crow;
      int o = wn + j * 16 + ccol;
#pragma unroll
      for (int r = 0; r < 4; ++r)
        omT[(size_t)k * 4096 + (b + r) * 64 + o] = f2b(acc[i][j][r]);
    }
}

// ================= bf16 transpose: omT [MD][4096] -> om [4096][MD] =============
__global__ __launch_bounds__(256) void transpose_om(const u16* __restrict__ omT,
                                                    u16* __restrict__ om) {
  __shared__ u16 S[64][65];
  const int bb = blockIdx.x;
  const int kb = blockIdx.y;
  const int t = threadIdx.x;
  const int r0 = t >> 6;
  const int c  = t & 63;
#pragma unroll
  for (int j = 0; j < 16; ++j) {
    int kr = r0 + j * 4;
    S[kr][c] = omT[(size_t)(kb * 64 + kr) * 4096 + bb * 64 + c];
  }
  __syncthreads();
#pragma unroll
  for (int j = 0; j < 16; ++j) {
    int br = r0 + j * 4;
    om[(size_t)(bb * 64 + br) * MD + kb * 64 + c] = S[c][br];
  }
}

extern "C" void kernel_launch(void* const* d_in, const int* in_sizes, int n_in,
                              void* d_out, int out_size, void* d_ws, size_t ws_size,
                              hipStream_t stream) {
  const float* x = (const float*)d_in[0];   // [B_][IC][NG]
  const float* w = (const float*)d_in[1];   // [IC][OC][MD]
  float* out = (float*)d_out;               // [B_][OC][NG]

  // ws layout (36 MB):
  //  [0,16M): xb bf16 | [16,18): M1 | [18,20): M3 | [20,24): xcT bf16
  //  [24,28): wT2 bf16 | [28,32): omT bf16 | [32,36): om bf16
  char* ws = (char*)d_ws;
  u16* xb  = (u16*)ws;
  u16* M1  = (u16*)(ws + (size_t)16 * 1024 * 1024);
  u16* M3  = (u16*)(ws + (size_t)18 * 1024 * 1024);
  u16* xcT = (u16*)(ws + (size_t)20 * 1024 * 1024);
  u16* wT2 = (u16*)(ws + (size_t)24 * 1024 * 1024);
  u16* omT = (u16*)(ws + (size_t)28 * 1024 * 1024);
  u16* om  = (u16*)(ws + (size_t)32 * 1024 * 1024);

  // fused prologue: cast + w-transpose + M1 + M3
  prep<<<16896, 256, 0, stream>>>(x, w, xb, wT2, M1, M3);

  // G1: xcT[512][4096] = M1[512][2048] * xb[4096][2048]^T  (K=2048), bf16 out
  gemm_bt3<2, 2, true><<<dim3((B_ * IC) / 64, MD / 64), 256, 0, stream>>>(
      M1, xb, xcT, NG, B_ * IC);

  // per-mode MFMA mix: omT[512][4096]
  mode_mix_mfma<<<MD, 256, 0, stream>>>(xcT, wT2, omT);

  // transpose to om[4096][512]
  transpose_om<<<dim3((B_ * OC) / 64, MD / 64), 256, 0, stream>>>(omT, om);

  // G3: out[4096][2048] = om[4096][512] * M3[2048][512]^T  (K=512), fp32 out
  gemm_bt3<4, 4, false><<<dim3(NG / 128, (B_ * OC) / 128), 256, 0, stream>>>(
      om, M3, out, MD, NG);
}

// Round 6
// 117.974 us; speedup vs baseline: 1.6855x; 1.1006x over previous
//
#include <hip/hip_runtime.h>

typedef unsigned short u16;
typedef __attribute__((ext_vector_type(8))) short short8;
typedef __attribute__((ext_vector_type(4))) float f32x4;

#define B_  64
#define IC  64
#define OC  64
#define NG  2048
#define MD  512

__device__ inline u16 f2b(float f) {
  unsigned u = __float_as_uint(f);
  unsigned r = (u + 0x7FFFu + ((u >> 16) & 1u)) >> 16;
  return (u16)r;
}

__device__ __forceinline__ float cosk(int k, int n) {
  int r = (k * n) % (2 * (NG - 1));
  return __cosf((float)r * (3.14159265358979323846f / (NG - 1)));
}

// async global->LDS, 16 B per lane. LDS dest is wave-uniform base + lane*16.
__device__ __forceinline__ void gld_lds16(const u16* g, const u16* l) {
  __builtin_amdgcn_global_load_lds(
      (__attribute__((address_space(1))) void*)(uintptr_t)(g),
      (__attribute__((address_space(3))) void*)(unsigned)(uintptr_t)(l),
      16, 0, 0);
}

// ================= fused prologue =================
// DCT-I reflection symmetry: cos(pi*k*(2047-n)/2047) = (-1)^k cos(pi*k*n/2047).
// grid: [0,4096) fold x -> e,o | [4096,4608) w->wT2 | [4608,6656) M1'' (perm rows)
//       [6656,8704) M3e/M3o
__global__ __launch_bounds__(256) void prep(
    const float* __restrict__ x, const float* __restrict__ w,
    u16* __restrict__ e, u16* __restrict__ o, u16* __restrict__ wT2,
    u16* __restrict__ M1p, u16* __restrict__ M3e, u16* __restrict__ M3o) {
  __shared__ float S[64][65];
  const int id = blockIdx.x;
  const int t = threadIdx.x;
  if (id < 4096) {                      // ---- e/o fold: one x row per block ----
    const float* xr = x + (size_t)id * NG;
    float4 f = *(const float4*)(xr + 4 * t);
    float4 b = *(const float4*)(xr + (2044 - 4 * t));
    ushort4 ev, ov;
    ev.x = f2b(f.x + b.w); ov.x = f2b(f.x - b.w);
    ev.y = f2b(f.y + b.z); ov.y = f2b(f.y - b.z);
    ev.z = f2b(f.z + b.y); ov.z = f2b(f.z - b.y);
    ev.w = f2b(f.w + b.x); ov.w = f2b(f.w - b.x);
    *(ushort4*)(e + (size_t)id * 1024 + 4 * t) = ev;
    *(ushort4*)(o + (size_t)id * 1024 + 4 * t) = ov;
  } else if (id < 4608) {               // ---- wT2[k][o*64+i] = w[i][o][k] ----
    int wb = id - 4096;
    int oo = wb & 63, kb = wb >> 6;
    int r0 = t >> 6, c = t & 63;
#pragma unroll
    for (int j = 0; j < 16; ++j) {
      int i = r0 + j * 4;
      S[i][c] = w[(size_t)(i * 64 + oo) * MD + kb * 64 + c];
    }
    __syncthreads();
#pragma unroll
    for (int j = 0; j < 16; ++j) {
      int kk = r0 + j * 4;
      wT2[(size_t)(kb * 64 + kk) * 4096 + oo * 64 + c] = f2b(S[c][kk]);
    }
  } else if (id < 6656) {               // ---- M1''[r][n], r<256: k=2r else k=2(r-256)+1 ----
    int idx = (id - 4608) * 256 + t;    // 512K
    int r = idx >> 10, n = idx & 1023;
    int k = (r < 256) ? 2 * r : 2 * (r - 256) + 1;
    float v = cosk(k, n) * ((n == 0) ? 1.0f : 2.0f);
    M1p[idx] = f2b(v);
  } else {                              // ---- M3e/M3o [1024][256] ----
    int idx = (id - 6656) * 256 + t;    // 512K
    int half = idx >> 18;
    int rem = idx & 262143;
    int n = rem >> 8, kp = rem & 255;
    if (half == 0) {
      float v = cosk(2 * kp, n) * ((kp == 0) ? 1.0f : 2.0f);
      M3e[rem] = f2b(v);
    } else {
      float v = cosk(2 * kp + 1, n) * 2.0f;
      M3o[rem] = f2b(v);
    }
  }
}

// ========== bf16 MFMA GEMM, Bt form, double-buffered async staging ==========
// C[m][n] = sum_k A[m][k]*Bt[n][k].  Bt = (blockIdx.y < splitY) ? Bt0 : Bt1.
// 256 thr = 4 waves (2x2), wave (MI*16)x(NI*16). TM=MI*32, TN=NI*32, BK=64.
// XOR swizzle: physical chunk = logical chunk ^ (row&7).
template<int MI, int NI, bool OUT_BF16>
__global__ __launch_bounds__(256, 2) void gemm_bt3(
    const u16* __restrict__ A,    // [M][K] bf16
    const u16* __restrict__ Bt0,  // [N][K] bf16
    const u16* __restrict__ Bt1,  // [N][K] bf16
    int splitY,
    void* __restrict__ Cv,        // [M][N] fp32 or bf16
    int K, int N) {
  constexpr int TM = MI * 32;
  constexpr int TN = NI * 32;
  constexpr int BK = 64;
  constexpr int ROWS = TM + TN;
  constexpr int CH = ROWS / 4;
  constexpr int NISSUE = CH / 8;
  constexpr int BUF = ROWS * BK;
  __shared__ u16 S[2 * BUF];

  const int tid  = threadIdx.x;
  const int lane = tid & 63;
  const int wave = tid >> 6;
  const int wm = (wave >> 1) * (MI * 16);
  const int wn = (wave & 1) * (NI * 16);
  const long bm = (long)blockIdx.y * TM;
  const long bn = (long)blockIdx.x * TN;
  const u16* Bt = ((int)blockIdx.y < splitY) ? Bt0 : Bt1;

  const int lrow = lane & 15;
  const int lhi  = lane >> 4;

  const int scc = (((lane & 7) ^ (lane >> 3)) * 8);
  const int r0 = wave * CH;

  const u16* gsrc[NISSUE];
  unsigned lofs[NISSUE];
#pragma unroll
  for (int ii = 0; ii < NISSUE; ++ii) {
    int rr = r0 + ii * 8 + (lane >> 3);
    gsrc[ii] = (rr < TM) ? (A + (bm + rr) * (long)K + scc)
                         : (Bt + (bn + rr - TM) * (long)K + scc);
    lofs[ii] = (unsigned)((r0 + ii * 8) * BK);
  }

  f32x4 acc[MI][NI] = {};

#pragma unroll
  for (int ii = 0; ii < NISSUE; ++ii)
    gld_lds16(gsrc[ii], &S[lofs[ii]]);

  int p = 0;
  for (int k0 = 0; k0 < K; k0 += BK) {
    __syncthreads();

    if (k0 + BK < K) {
#pragma unroll
      for (int ii = 0; ii < NISSUE; ++ii)
        gld_lds16(gsrc[ii] + k0 + BK, &S[(1 - p) * BUF + lofs[ii]]);
    }

    const u16* Sp = &S[p * BUF];
#pragma unroll
    for (int kk8 = 0; kk8 < 8; kk8 += 4) {
      short8 af[MI], bfr[NI];
#pragma unroll
      for (int i = 0; i < MI; ++i) {
        int pch = ((kk8 + lhi) ^ (lane & 7));
        af[i] = *(const short8*)&Sp[(wm + i * 16 + lrow) * BK + pch * 8];
      }
#pragma unroll
      for (int j = 0; j < NI; ++j) {
        int pch = ((kk8 + lhi) ^ (lane & 7));
        bfr[j] = *(const short8*)&Sp[(TM + wn + j * 16 + lrow) * BK + pch * 8];
      }
#pragma unroll
      for (int i = 0; i < MI; ++i)
#pragma unroll
        for (int j = 0; j < NI; ++j)
          acc[i][j] = __builtin_amdgcn_mfma_f32_16x16x32_bf16(af[i], bfr[j], acc[i][j], 0, 0, 0);
    }
    p ^= 1;
  }

  const int crow = (lane >> 4) * 4;
  const int ccol = lane & 15;
#pragma unroll
  for (int i = 0; i < MI; ++i)
#pragma unroll
    for (int j = 0; j < NI; ++j) {
      long gm = bm + wm + i * 16 + crow;
      long gn = bn + wn + j * 16 + ccol;
      if (OUT_BF16) {
        u16* cp = (u16*)Cv + gm * (long)N + gn;
#pragma unroll
        for (int r = 0; r < 4; ++r)
          cp[(long)r * N] = f2b(acc[i][j][r]);
      } else {
        float* cp = (float*)Cv + gm * (long)N + gn;
#pragma unroll
        for (int r = 0; r < 4; ++r)
          cp[(long)r * N] = acc[i][j][r];
      }
    }
}

// ================= per-mode 64x64x64 mix via MFMA =================
// omT[k][b*64+o] = sum_i xcT[rk(k)][b*64+i] * wT2[k][o*64+i]
// xcT rows are permuted: row r<256 holds even k=2r, else odd.
__global__ __launch_bounds__(256, 4) void mode_mix_mfma(
    const u16* __restrict__ xcT,   // [512][4096] bf16 (permuted rows)
    const u16* __restrict__ wT2,   // [512][4096] bf16 (o*64+i order)
    u16* __restrict__ omT) {       // [512][4096] bf16 (k order)
  constexpr int PK = 72;
  __shared__ u16 S[128 * PK];
  const int k = blockIdx.x;
  const int rk = (k & 1) ? 256 + (k >> 1) : (k >> 1);
  const int t = threadIdx.x;

#pragma unroll
  for (int c = 0; c < 4; ++c) {
    int ch = t + c * 256;
    int half = ch >> 9, cc = ch & 511;
    int row = cc >> 3, col8 = cc & 7;
    const u16* src = half ? (wT2 + (size_t)k * 4096)
                          : (xcT + (size_t)rk * 4096);
    uint4 v = *(const uint4*)(src + row * 64 + col8 * 8);
    *(uint4*)&S[(half * 64 + row) * PK + col8 * 8] = v;
  }
  __syncthreads();

  const int lane = t & 63;
  const int wave = t >> 6;
  const int wm = (wave >> 1) * 32;
  const int wn = (wave & 1) * 32;
  const int lrow = lane & 15;
  const int lhi  = lane >> 4;

  f32x4 acc[2][2] = {};
#pragma unroll
  for (int kk8 = 0; kk8 < 8; kk8 += 4) {
    short8 af[2], bfr[2];
#pragma unroll
    for (int i = 0; i < 2; ++i)
      af[i] = *(const short8*)&S[(wm + i * 16 + lrow) * PK + (kk8 + lhi) * 8];
#pragma unroll
    for (int j = 0; j < 2; ++j)
      bfr[j] = *(const short8*)&S[(64 + wn + j * 16 + lrow) * PK + (kk8 + lhi) * 8];
#pragma unroll
    for (int i = 0; i < 2; ++i)
#pragma unroll
      for (int j = 0; j < 2; ++j)
        acc[i][j] = __builtin_amdgcn_mfma_f32_16x16x32_bf16(af[i], bfr[j], acc[i][j], 0, 0, 0);
  }

  const int crow = (lane >> 4) * 4;
  const int ccol = lane & 15;
#pragma unroll
  for (int i = 0; i < 2; ++i)
#pragma unroll
    for (int j = 0; j < 2; ++j) {
      int b = wm + i * 16 + crow;
      int oo = wn + j * 16 + ccol;
#pragma unroll
      for (int r = 0; r < 4; ++r)
        omT[(size_t)k * 4096 + (b + r) * 64 + oo] = f2b(acc[i][j][r]);
    }
}

// ====== bf16 transpose with even/odd column split: omT [512][4096] -> om' ======
// om'[bo][k'] : k'<256 holds k=2k' (even), k'>=256 holds k=2(k'-256)+1 (odd)
__global__ __launch_bounds__(256) void transpose_om(const u16* __restrict__ omT,
                                                    u16* __restrict__ omp) {
  __shared__ u16 S[64][65];
  const int bb = blockIdx.x;
  const int kb = blockIdx.y;
  const int t = threadIdx.x;
  const int r0 = t >> 6;
  const int c  = t & 63;
#pragma unroll
  for (int j = 0; j < 16; ++j) {
    int kr = r0 + j * 4;
    S[kr][c] = omT[(size_t)(kb * 64 + kr) * 4096 + bb * 64 + c];
  }
  __syncthreads();
  const int col = ((c & 1) ? 256 : 0) + kb * 32 + (c >> 1);
#pragma unroll
  for (int j = 0; j < 16; ++j) {
    int br = r0 + j * 4;
    omp[(size_t)(bb * 64 + br) * MD + col] = S[c][br];
  }
}

// ================= G3: dual half-K GEMM + in-wave butterfly =================
// E[bo][n] = sum_{k'<256} om'[bo][k']   * M3e[n][k']
// O[bo][n] = sum_{k'<256} om'[bo][256+k']*M3o[n][k']
// out[bo][n] = E+O ; out[bo][2047-n] = E-O   (n < 1024)
// Block: 128 bo x 64 n. 4 waves stacked (32 bo each, MI=2, NI=4). BK=64, 4 steps.
// LDS rows: [0,128) A_e | [128,256) A_o | [256,320) Be | [320,384) Bo; 48 KB.
__global__ __launch_bounds__(256, 2) void gemm_g3(
    const u16* __restrict__ omp,   // [4096][512] bf16 (even|odd halves)
    const u16* __restrict__ M3e,   // [1024][256] bf16
    const u16* __restrict__ M3o,   // [1024][256] bf16
    float* __restrict__ out) {     // [4096][2048] fp32
  constexpr int BK = 64;
  constexpr int ROWS = 384;
  constexpr int CH = ROWS / 4;     // 96 rows per wave
  constexpr int NISSUE = CH / 8;   // 12
  __shared__ u16 S[ROWS * BK];

  const int tid  = threadIdx.x;
  const int lane = tid & 63;
  const int wave = tid >> 6;
  const long bm = (long)blockIdx.y * 128;
  const int n0 = blockIdx.x * 64;

  const int lrow = lane & 15;
  const int lhi  = lane >> 4;
  const int scc = (((lane & 7) ^ (lane >> 3)) * 8);
  const int r0 = wave * CH;

  const u16* gsrc[NISSUE];
  unsigned lofs[NISSUE];
#pragma unroll
  for (int ii = 0; ii < NISSUE; ++ii) {
    int rr = r0 + ii * 8 + (lane >> 3);
    const u16* p;
    if (rr < 128)       p = omp + (bm + rr) * (long)512 + scc;
    else if (rr < 256)  p = omp + (bm + rr - 128) * (long)512 + 256 + scc;
    else if (rr < 320)  p = M3e + (n0 + rr - 256) * (long)256 + scc;
    else                p = M3o + (n0 + rr - 320) * (long)256 + scc;
    gsrc[ii] = p;
    lofs[ii] = (unsigned)((r0 + ii * 8) * BK);
  }

  f32x4 accE[2][4] = {};
  f32x4 accO[2][4] = {};

  for (int k0 = 0; k0 < 256; k0 += BK) {
#pragma unroll
    for (int ii = 0; ii < NISSUE; ++ii)
      gld_lds16(gsrc[ii] + k0, &S[lofs[ii]]);
    __syncthreads();

#pragma unroll
    for (int kk8 = 0; kk8 < 8; kk8 += 4) {
      int pch = ((kk8 + lhi) ^ (lane & 7));
      short8 aE[2], aO[2], bE[4], bO[4];
#pragma unroll
      for (int i = 0; i < 2; ++i) {
        aE[i] = *(const short8*)&S[(wave * 32 + i * 16 + lrow) * BK + pch * 8];
        aO[i] = *(const short8*)&S[(128 + wave * 32 + i * 16 + lrow) * BK + pch * 8];
      }
#pragma unroll
      for (int j = 0; j < 4; ++j) {
        bE[j] = *(const short8*)&S[(256 + j * 16 + lrow) * BK + pch * 8];
        bO[j] = *(const short8*)&S[(320 + j * 16 + lrow) * BK + pch * 8];
      }
#pragma unroll
      for (int i = 0; i < 2; ++i)
#pragma unroll
        for (int j = 0; j < 4; ++j) {
          accE[i][j] = __builtin_amdgcn_mfma_f32_16x16x32_bf16(aE[i], bE[j], accE[i][j], 0, 0, 0);
          accO[i][j] = __builtin_amdgcn_mfma_f32_16x16x32_bf16(aO[i], bO[j], accO[i][j], 0, 0, 0);
        }
    }
    __syncthreads();
  }

  const int crow = (lane >> 4) * 4;
  const int ccol = lane & 15;
#pragma unroll
  for (int i = 0; i < 2; ++i)
#pragma unroll
    for (int j = 0; j < 4; ++j) {
      long bo = bm + wave * 32 + i * 16 + crow;
      int n = n0 + j * 16 + ccol;
      float* op = out + bo * (long)NG;
#pragma unroll
      for (int r = 0; r < 4; ++r) {
        float E = accE[i][j][r], O = accO[i][j][r];
        op[(long)r * NG + n] = E + O;
        op[(long)r * NG + (NG - 1 - n)] = E - O;
      }
    }
}

extern "C" void kernel_launch(void* const* d_in, const int* in_sizes, int n_in,
                              void* d_out, int out_size, void* d_ws, size_t ws_size,
                              hipStream_t stream) {
  const float* x = (const float*)d_in[0];   // [B_][IC][NG]
  const float* w = (const float*)d_in[1];   // [IC][OC][MD]
  float* out = (float*)d_out;               // [B_][OC][NG]

  // ws layout (36 MB):
  //  [0,8M): e | [8,16M): o | [16,17M): M1'' | [17,17.5M): M3e | [17.5,18M): M3o
  //  [20,24M): xcT bf16 (permuted rows) | [24,28M): wT2 | [28,32M): omT | [32,36M): om'
  char* ws = (char*)d_ws;
  u16* e    = (u16*)ws;
  u16* o    = (u16*)(ws + (size_t)8 * 1024 * 1024);
  u16* M1p  = (u16*)(ws + (size_t)16 * 1024 * 1024);
  u16* M3e  = (u16*)(ws + (size_t)17 * 1024 * 1024);
  u16* M3o  = (u16*)(ws + (size_t)17 * 1024 * 1024 + 512 * 1024);
  u16* xcT  = (u16*)(ws + (size_t)20 * 1024 * 1024);
  u16* wT2  = (u16*)(ws + (size_t)24 * 1024 * 1024);
  u16* omT  = (u16*)(ws + (size_t)28 * 1024 * 1024);
  u16* omp  = (u16*)(ws + (size_t)32 * 1024 * 1024);

  // fused prologue: e/o fold + w-transpose + M1'' + M3e/M3o
  prep<<<8704, 256, 0, stream>>>(x, w, e, o, wT2, M1p, M3e, M3o);

  // G1: xcT[512][4096] = M1''[512][1024] * {e|o}[4096][1024]^T  (K=1024)
  // rows r<256 (even k) pair with e -> blockIdx.y<4
  gemm_bt3<2, 2, true><<<dim3((B_ * IC) / 64, 512 / 64), 256, 0, stream>>>(
      M1p, e, o, 4, xcT, 1024, B_ * IC);

  // per-mode MFMA mix: omT[512][4096]
  mode_mix_mfma<<<MD, 256, 0, stream>>>(xcT, wT2, omT);

  // transpose + even/odd split to om'[4096][512]
  transpose_om<<<dim3((B_ * OC) / 64, MD / 64), 256, 0, stream>>>(omT, omp);

  // G3: dual half-K GEMM + butterfly -> out[4096][2048]
  gemm_g3<<<dim3(1024 / 64, (B_ * OC) / 128), 256, 0, stream>>>(omp, M3e, M3o, out);
}